// Round 6
// baseline (412.665 us; speedup 1.0000x reference)
//
#include <hip/hip_runtime.h>
#include <stdint.h>

#define OUT_DIM 8192
#define IN_DIM  8192
#define GS      128
#define MROWS   32
#define NSPLIT  8           // split-K chunks of 1024
#define KCHUNK  1024
#define KS      64          // k-ints staged per block-stage
#define NSTG    (KCHUNK / KS)   // 16
#define PART_ELEMS (MROWS * OUT_DIM)

typedef __attribute__((ext_vector_type(8))) short bf16x8;   // MFMA A/B frag (4 VGPR)
typedef __attribute__((ext_vector_type(4))) float f32x4;    // MFMA C/D frag
typedef __attribute__((ext_vector_type(8))) unsigned short u16x8;
typedef __attribute__((ext_vector_type(2))) unsigned short u16x2;
typedef __attribute__((ext_vector_type(4))) unsigned int   u32x4;

__device__ __forceinline__ unsigned short f2bf_rne(float f) {
    uint32_t v = __builtin_bit_cast(uint32_t, f);
    v += 0x7FFFu + ((v >> 16) & 1u);
    return (unsigned short)(v >> 16);
}

// x (32x8192 fp32) -> bf16 workspace. Round-0 proven. ~3us.
__global__ __launch_bounds__(256) void prep_xbf(const float* __restrict__ x,
                                                unsigned short* __restrict__ xbf) {
    int i = (blockIdx.x * 256 + threadIdx.x) * 8;
    float4 a = *(const float4*)(x + i);
    float4 b = *(const float4*)(x + i + 4);
    float f[8] = {a.x, a.y, a.z, a.w, b.x, b.y, b.z, b.w};
    u16x8 u;
#pragma unroll
    for (int j = 0; j < 8; ++j) u[j] = f2bf_rne(f[j]);
    *(u16x8*)(xbf + i) = u;
}

// Packed conversion (round-1 correctness-proven): two ternary int32 -> one dword
// of two bf16 weights. t in {-1,0,1}: v = p|sign(t); r = v * |t| (v_pk_mul_lo_u16).
__device__ __forceinline__ unsigned int cvt2(int t0, int t1, unsigned int p32) {
    unsigned int t16 = __builtin_amdgcn_perm((unsigned int)t1, (unsigned int)t0,
                                             0x05040100u);  // lo=t0.l16, hi=t1.l16
    unsigned int v   = p32 | (t16 & 0x80008000u);
    u16x2 r = __builtin_bit_cast(u16x2, v) *
              __builtin_bit_cast(u16x2, t16 & 0x00010001u);
    return __builtin_bit_cast(unsigned int, r);
}

__device__ __forceinline__ bf16x8 conv8(const int4 wa, const int4 wb, unsigned int p32) {
    u32x4 d;
    d[0] = cvt2(wa.x, wa.y, p32);
    d[1] = cvt2(wa.z, wa.w, p32);
    d[2] = cvt2(wb.x, wb.y, p32);
    d[3] = cvt2(wb.z, wb.w, p32);
    return __builtin_bit_cast(bf16x8, d);
}

// Cross-round evidence: R3-R0=+48us from doubling x line-traffic; R5 (coalesced
// weights, x still gathered) stuck at ~143us -> the x A-frag gather (16 rows x
// 64B @16KB stride, L1-thrashing) is the ~100us bottleneck; occupancy-doubling
// null (R4) because L1/TCP is per-CU. Fix: stage BOTH w and x in LDS via fully
// coalesced loads; all strided fragment reads move to the LDS pipe.
// Per stage (KS=64 k): w 16KB (4x int4/thread, 8 full lines/instr, HBM) +
// x 4KB (1x 16B/thread, 8 full lines/instr, L2-hot). 2-ahead register pipeline:
// iter s issues loads for s+2, writes s+1 to LDS after barrier1 -> HBM latency
// spans a full stage. Single-buffer LDS, 2 barriers/stage, 21.5KB/block.
// XOR-swizzle (col ^= (row&7)<<3, 16B-aligned) + pad keeps frag reads ~2-way.
#define WSW(r, c) ((c) ^ (((r) & 7) << 3))
__global__ __launch_bounds__(256) void ternary_gemm(
    const int* __restrict__ tern, const float* __restrict__ scales,
    const unsigned short* __restrict__ xbf, float* __restrict__ part) {
    __shared__ __align__(16) int            lw[64][68];   // stride 272B (17x16)
    __shared__ __align__(16) unsigned short lx[32][72];   // stride 144B (9x16)

    const int tid  = threadIdx.x;
    const int wv   = tid >> 6;
    const int lane = tid & 63;
    const int n    = lane & 15;
    const int quad = lane >> 4;

    const int otile = blockIdx.x & 127;        // 128 o-tiles of 64
    const int kc    = blockIdx.x >> 7;         // 0..7 split-K chunk
    const int o0    = otile << 6;
    const int o     = o0 + (wv << 4) + n;
    const int kpos0 = kc << 10;

    // w staging: thread -> 4 rows (srow+{0,16,32,48}), 16B col; lanes 0..15
    // cover 256B contiguous per row.
    const int srow = tid >> 4;                 // 0..15
    const int scol = (tid & 15) << 2;          // int col 0..60
    const int* __restrict__ wbase = tern + (size_t)o0 * IN_DIM + kpos0 + scol;

    // x staging: thread -> 1 row (0..31), 16B col; lanes 0..7 cover 128B/row.
    const int xrow = tid >> 3;                 // 0..31
    const int xcol = (tid & 7) << 3;           // bf16 col 0..56
    const unsigned short* __restrict__ xbase =
        xbf + (size_t)xrow * IN_DIM + kpos0 + xcol;

    const float* __restrict__ sp = scales + o * (IN_DIM / GS) + (kc << 3);

    f32x4 acc0 = {0.f, 0.f, 0.f, 0.f};
    f32x4 acc1 = {0.f, 0.f, 0.f, 0.f};

#define WLOAD(d0, d1, d2, d3, T) do { const int* wb = wbase + (T) * KS;        \
        d0 = *(const int4*)(wb + (size_t) srow       * IN_DIM);                \
        d1 = *(const int4*)(wb + (size_t)(srow + 16) * IN_DIM);                \
        d2 = *(const int4*)(wb + (size_t)(srow + 32) * IN_DIM);                \
        d3 = *(const int4*)(wb + (size_t)(srow + 48) * IN_DIM); } while (0)
#define XLOAD(d, T) (d) = *(const bf16x8*)(xbase + (T) * KS)
#define WWRITE(s0, s1, s2, s3) do { const int c = WSW(srow, scol);             \
        *(int4*)&lw[srow     ][c] = s0; *(int4*)&lw[srow + 16][c] = s1;        \
        *(int4*)&lw[srow + 32][c] = s2; *(int4*)&lw[srow + 48][c] = s3; } while (0)
#define XWRITE(v) *(bf16x8*)&lx[xrow][WSW(xrow, xcol)] = (v)

    int4 wn0, wn1, wn2, wn3; bf16x8 xn;
    // stage 0: load + write directly (fresh LDS, no prior readers)
    WLOAD(wn0, wn1, wn2, wn3, 0); XLOAD(xn, 0);
    WWRITE(wn0, wn1, wn2, wn3);   XWRITE(xn);
    // stage 1 held in "next" regs
    WLOAD(wn0, wn1, wn2, wn3, 1); XLOAD(xn, 1);
    int4 wf0 = wn0, wf1 = wn1, wf2 = wn2, wf3 = wn3; bf16x8 xf = xn;
    __syncthreads();

    const int lrow = (wv << 4) + n;
    const int qo   = quad << 3;

#pragma unroll 1
    for (int s = 0; s < NSTG; ++s) {
        if (s + 2 < NSTG) { WLOAD(wf0, wf1, wf2, wf3, s + 2); XLOAD(xf, s + 2); }
        const unsigned int ph  = f2bf_rne(sp[s >> 1]);   // group = kc*8 + s/2
        const unsigned int p32 = ph | (ph << 16);
#pragma unroll
        for (int half = 0; half < 2; ++half) {
            const int kk  = (half << 5) + qo;            // k-offset within stage
            const int wc  = WSW(lrow, kk);
            int4 w0 = *(const int4*)&lw[lrow][wc];
            int4 w1 = *(const int4*)&lw[lrow][wc + 4];   // wc%8==0 -> same 8-blk
            bf16x8 a0 = *(const bf16x8*)&lx[n     ][WSW(n, kk)];
            bf16x8 a1 = *(const bf16x8*)&lx[16 + n][WSW(n, kk)];  // (16+n)&7==n&7
            bf16x8 bfr = conv8(w0, w1, p32);
            acc0 = __builtin_amdgcn_mfma_f32_16x16x32_bf16(a0, bfr, acc0, 0, 0, 0);
            acc1 = __builtin_amdgcn_mfma_f32_16x16x32_bf16(a1, bfr, acc1, 0, 0, 0);
        }
        __syncthreads();                                 // all done reading s
        if (s + 1 < NSTG) { WWRITE(wn0, wn1, wn2, wn3); XWRITE(xn); }
        __syncthreads();                                 // s+1 visible
        wn0 = wf0; wn1 = wf1; wn2 = wf2; wn3 = wf3; xn = xf;
    }
#undef WLOAD
#undef XLOAD
#undef WWRITE
#undef XWRITE

    // D layout: col = lane&15 (=o), row t = quad*4 + reg. Plain stores.
    float* __restrict__ prow = part + (size_t)kc * PART_ELEMS;
#pragma unroll
    for (int r = 0; r < 4; ++r) {
        prow[(quad * 4 + r) * OUT_DIM + o]      = acc0[r];
        prow[(quad * 4 + r + 16) * OUT_DIM + o] = acc1[r];
    }
}

// out = sum over 8 split-K partials. 256 blocks x 256 thr x float4.
__global__ __launch_bounds__(256) void reduce_parts(const float* __restrict__ part,
                                                    float* __restrict__ out) {
    const int i = (blockIdx.x * 256 + threadIdx.x) * 4;
    float4 s = *(const float4*)(part + i);
#pragma unroll
    for (int kc = 1; kc < NSPLIT; ++kc) {
        float4 v = *(const float4*)(part + (size_t)kc * PART_ELEMS + i);
        s.x += v.x; s.y += v.y; s.z += v.z; s.w += v.w;
    }
    *(float4*)(out + i) = s;
}

extern "C" void kernel_launch(void* const* d_in, const int* in_sizes, int n_in,
                              void* d_out, int out_size, void* d_ws, size_t ws_size,
                              hipStream_t stream) {
    const float* x      = (const float*)d_in[0];
    const int*   tern   = (const int*)d_in[1];
    const float* scales = (const float*)d_in[2];
    float* out = (float*)d_out;

    unsigned short* xbf = (unsigned short*)d_ws;                 // 512 KB
    float* part = (float*)((char*)d_ws + (512 << 10));           // 8 MB

    prep_xbf<<<128, 256, 0, stream>>>(x, xbf);
    ternary_gemm<<<128 * NSPLIT, 256, 0, stream>>>(tern, scales, xbf, part);
    reduce_parts<<<256, 256, 0, stream>>>(part, out);
}

// Round 7
// 382.397 us; speedup vs baseline: 1.0792x; 1.0792x over previous
//
#include <hip/hip_runtime.h>
#include <stdint.h>

#define OUT_DIM 8192
#define IN_DIM  8192
#define GS      128
#define MROWS   32
#define NSPLIT  8             // split-K chunks of 1024
#define KCHUNK  1024
#define KSTG    128           // k-ints per stage = exactly one scale group
#define NSTG    (KCHUNK / KSTG)   // 8
#define PART_ELEMS (MROWS * OUT_DIM)

typedef __attribute__((ext_vector_type(8))) short bf16x8;   // MFMA A/B frag (4 VGPR)
typedef __attribute__((ext_vector_type(4))) float f32x4;    // MFMA C/D frag
typedef __attribute__((ext_vector_type(8))) unsigned short u16x8;
typedef __attribute__((ext_vector_type(2))) unsigned short u16x2;
typedef __attribute__((ext_vector_type(4))) unsigned int   u32x4;

__device__ __forceinline__ unsigned short f2bf_rne(float f) {
    uint32_t v = __builtin_bit_cast(uint32_t, f);
    v += 0x7FFFu + ((v >> 16) & 1u);
    return (unsigned short)(v >> 16);
}

// x (32x8192 fp32) -> bf16 workspace. Round-0 proven. ~3us.
__global__ __launch_bounds__(256) void prep_xbf(const float* __restrict__ x,
                                                unsigned short* __restrict__ xbf) {
    int i = (blockIdx.x * 256 + threadIdx.x) * 8;
    float4 a = *(const float4*)(x + i);
    float4 b = *(const float4*)(x + i + 4);
    float f[8] = {a.x, a.y, a.z, a.w, b.x, b.y, b.z, b.w};
    u16x8 u;
#pragma unroll
    for (int j = 0; j < 8; ++j) u[j] = f2bf_rne(f[j]);
    *(u16x8*)(xbf + i) = u;
}

// Packed conversion (R1/R6 correctness-proven): two ternary int32 -> one dword
// of two bf16 weights. t in {-1,0,1}: v = p|sign(t); r = v * |t| (v_pk_mul_lo_u16).
__device__ __forceinline__ unsigned int cvt2(int t0, int t1, unsigned int p32) {
    unsigned int t16 = __builtin_amdgcn_perm((unsigned int)t1, (unsigned int)t0,
                                             0x05040100u);  // lo=t0.l16, hi=t1.l16
    unsigned int v   = p32 | (t16 & 0x80008000u);
    u16x2 r = __builtin_bit_cast(u16x2, v) *
              __builtin_bit_cast(u16x2, t16 & 0x00010001u);
    return __builtin_bit_cast(unsigned int, r);
}

__device__ __forceinline__ bf16x8 conv8(const int4 wa, const int4 wb, unsigned int p32) {
    u32x4 d;
    d[0] = cvt2(wa.x, wa.y, p32);
    d[1] = cvt2(wa.z, wa.w, p32);
    d[2] = cvt2(wb.x, wb.y, p32);
    d[3] = cvt2(wb.z, wb.w, p32);
    return __builtin_bit_cast(bf16x8, d);
}

// Async global->LDS, 16B per lane. Global source is PER-LANE; LDS dest is
// wave-uniform base + lane*16 (linear). Compiler never auto-emits this.
__device__ __forceinline__ void glds16(const int* g, int* l) {
    __builtin_amdgcn_global_load_lds(
        (const __attribute__((address_space(1))) void*)g,
        (__attribute__((address_space(3))) void*)l, 16, 0, 0);
}

// Evidence through R6: gather-free LDS staging (R6) ~= gather kernel + barriers
// (R5) and both LOSE to the barrier-free gather kernel (R0, ~119us). The cost
// is the staging structure itself: 2 syncthreads/stage, each a full vmcnt(0)
// drain coupled to the reg->LDS round-trip (the m97-documented stall). Fix =
// the guide's proven pattern: global_load_lds staging (no VGPR round-trip, no
// ds_write), ONE barrier/stage, HW streams weights to LDS while waves compute.
// Block = 4 waves = 64 o x 32 t; stage = 64 rows x 128 k = one scale group;
// LDS [2][64][128] ints = 64KB dbuf -> 2 blocks/CU. Per stage per wave: 8 glds
// (1KB linear LDS = 2 rows x 512B contiguous global), then 4 k-halves of
// {2x ds_read_b128 w, 2x global bf16x8 x (L2-hot, R0-proven), conv8, 2 MFMA}.
// The stage-end syncthreads' implicit drain doubles as the glds wait, hidden
// under ~600cy of compute.
__global__ __launch_bounds__(256) void ternary_gemm(
    const int* __restrict__ tern, const float* __restrict__ scales,
    const unsigned short* __restrict__ xbf, float* __restrict__ part) {
    __shared__ __align__(16) int lw[2][64][KSTG];   // 64 KB

    const int tid  = threadIdx.x;
    const int wv   = tid >> 6;
    const int lane = tid & 63;
    const int n    = lane & 15;
    const int quad = lane >> 4;

    const int otile = blockIdx.x & 127;        // 128 o-tiles of 64
    const int kc    = blockIdx.x >> 7;         // 0..7 split-K chunk
    const int o0    = otile << 6;
    const int o     = o0 + (wv << 4) + n;
    const int kpos0 = kc << 10;

    // staging: wave wv fills rows wv*16..wv*16+15; instr i covers rows
    // {wv*16+2i, +1}; lane -> (row_half = lane>>5, 16B col = lane&31).
    const int rbase = (wv << 4);
    const int* __restrict__ gstg =
        tern + kpos0 + ((lane & 31) << 2) + (size_t)(o0 + rbase + (lane >> 5)) * IN_DIM;

    const unsigned short* __restrict__ xr0 = xbf + n * IN_DIM + kpos0 + (quad << 3);
    const unsigned short* __restrict__ xr1 = xbf + (16 + n) * IN_DIM + kpos0 + (quad << 3);
    const float* __restrict__ sp = scales + o * (IN_DIM / GS) + (kc << 3);

    f32x4 acc0 = {0.f, 0.f, 0.f, 0.f};
    f32x4 acc1 = {0.f, 0.f, 0.f, 0.f};

#define GLDS_STAGE(BUF, STG) do {                                              \
        const int* gs = gstg + (STG) * KSTG;                                   \
        _Pragma("unroll")                                                      \
        for (int i = 0; i < 8; ++i)                                            \
            glds16(gs + (size_t)(i << 1) * IN_DIM,                             \
                   &lw[BUF][rbase + (i << 1)][0]);                             \
    } while (0)

    GLDS_STAGE(0, 0);
    __syncthreads();                           // drain: stage 0 resident

    const int lrow = (wv << 4) + n;

#pragma unroll 1
    for (int s = 0; s < NSTG; ++s) {
        const int buf = s & 1;
        if (s + 1 < NSTG) GLDS_STAGE(buf ^ 1, s + 1);   // in flight during compute
        const unsigned int ph  = f2bf_rne(sp[s]);       // stage == scale group
        const unsigned int p32 = ph | (ph << 16);
        const int ks = s * KSTG;
#pragma unroll
        for (int half = 0; half < 4; ++half) {
            const int koff = (half << 5) + (quad << 3); // ints within stage
            int4 w0 = *(const int4*)&lw[buf][lrow][koff];
            int4 w1 = *(const int4*)&lw[buf][lrow][koff + 4];
            bf16x8 a0 = *(const bf16x8*)(xr0 + ks + (half << 5));
            bf16x8 a1 = *(const bf16x8*)(xr1 + ks + (half << 5));
            bf16x8 bfr = conv8(w0, w1, p32);
            acc0 = __builtin_amdgcn_mfma_f32_16x16x32_bf16(a0, bfr, acc0, 0, 0, 0);
            acc1 = __builtin_amdgcn_mfma_f32_16x16x32_bf16(a1, bfr, acc1, 0, 0, 0);
        }
        __syncthreads();   // one barrier/stage: waits glds(s+1), fences buf reuse
    }
#undef GLDS_STAGE

    // D layout: col = lane&15 (=o), row t = quad*4 + reg. Plain stores.
    float* __restrict__ prow = part + (size_t)kc * PART_ELEMS;
#pragma unroll
    for (int r = 0; r < 4; ++r) {
        prow[(quad * 4 + r) * OUT_DIM + o]      = acc0[r];
        prow[(quad * 4 + r + 16) * OUT_DIM + o] = acc1[r];
    }
}

// out = sum over 8 split-K partials. 256 blocks x 256 thr x float4.
__global__ __launch_bounds__(256) void reduce_parts(const float* __restrict__ part,
                                                    float* __restrict__ out) {
    const int i = (blockIdx.x * 256 + threadIdx.x) * 4;
    float4 s = *(const float4*)(part + i);
#pragma unroll
    for (int kc = 1; kc < NSPLIT; ++kc) {
        float4 v = *(const float4*)(part + (size_t)kc * PART_ELEMS + i);
        s.x += v.x; s.y += v.y; s.z += v.z; s.w += v.w;
    }
    *(float4*)(out + i) = s;
}

extern "C" void kernel_launch(void* const* d_in, const int* in_sizes, int n_in,
                              void* d_out, int out_size, void* d_ws, size_t ws_size,
                              hipStream_t stream) {
    const float* x      = (const float*)d_in[0];
    const int*   tern   = (const int*)d_in[1];
    const float* scales = (const float*)d_in[2];
    float* out = (float*)d_out;

    unsigned short* xbf = (unsigned short*)d_ws;                 // 512 KB
    float* part = (float*)((char*)d_ws + (512 << 10));           // 8 MB

    prep_xbf<<<128, 256, 0, stream>>>(x, xbf);
    ternary_gemm<<<128 * NSPLIT, 256, 0, stream>>>(tern, scales, xbf, part);
    reduce_parts<<<256, 256, 0, stream>>>(part, out);
}